// Round 16
// baseline (507.639 us; speedup 1.0000x reference)
//
#include <hip/hip_runtime.h>

#define N_NODES 100000
#define N_EDGES 1600000
#define DH 128
#define DOUT 64
#define EPS 1e-6f
#define NBINS 8
#define BINW 12500  // ceil(N_NODES / NBINS)
#define NREP 64     // stats replica buffers
#define NGRP128 ((N_NODES + 127) / 128)  // 128-node groups = 782
#define SRCMASK 0x1FFFFu                 // low 17 bits: src node id
#define WSCALE (1.0f / 32767.0f)         // 15-bit fixed-point weight

typedef __attribute__((ext_vector_type(8))) short s8v;    // 8 bf16 (4 VGPRs)
typedef __attribute__((ext_vector_type(4))) float f32x4;  // MFMA accumulator

__device__ inline unsigned bfround(float f) {  // f32 -> bf16 bits, round-nearest-even
    unsigned u = __float_as_uint(f);
    return (u + 0x7fffu + ((u >> 16) & 1u)) >> 16;
}
__device__ inline unsigned pack2(float a, float b) { return bfround(a) | (bfround(b) << 16); }
__device__ inline float blo(unsigned u) { return __uint_as_float(u << 16); }
__device__ inline float bhi(unsigned u) { return __uint_as_float(u & 0xffff0000u); }

// ------------- MFMA GEMM: Y(bf16, SLICE-MAJOR [CT][N][8 uints]) = f(X)@W + b -------------
// PN=0: X f32 row-major.  PN>=1: X bf16 slice-major [8][N][8 uints], f=relu((X-mu)*inv),
// mu/inv finalized in-block from replica partials.  PN=2: + relu((Xb-muB)*invB) likewise.
template <int COLS, int PN>
__global__ __launch_bounds__(256) void gemm_mfma(const void* __restrict__ Xav,
                                                 const float* __restrict__ cs_partA,
                                                 const float* __restrict__ ss_partA,
                                                 const unsigned* __restrict__ Xbu2,
                                                 const float* __restrict__ cs_partB,
                                                 const float* __restrict__ ss_partB,
                                                 const float* __restrict__ W,
                                                 const float* __restrict__ bias,
                                                 unsigned* __restrict__ Y, int nrows) {
    constexpr int CT = COLS / 16;       // col tiles per wave == slice count of Y
    __shared__ unsigned wtu[COLS][64];  // W^T bf16 pairs: [c][k/2], swizzled
    __shared__ unsigned xbu[64][64];    // X bf16 pairs:   [r][k/2], swizzled
    __shared__ float mulds[2][128];
    __shared__ float invlds[2];
    __shared__ float sstotlds[2];

    const int tid = threadIdx.x;
    const int wv = tid >> 6;
    const int lane = tid & 63;

    // ---- stage W^T as bf16 (once per block) ----
    {
        ushort* wts = (ushort*)wtu;
        constexpr int NV4 = 128 * COLS / 4;
        for (int i = tid; i < NV4; i += 256) {
            int k = i / (COLS / 4);
            int c4 = i % (COLS / 4);
            float4 w4 = reinterpret_cast<const float4*>(W)[i];
            float vals[4] = {w4.x, w4.y, w4.z, w4.w};
            int u = k >> 1, kb = k & 1;
#pragma unroll
            for (int j = 0; j < 4; ++j) {
                int c = c4 * 4 + j;
                int us = u ^ ((c & 7) << 2);
                wts[c * 128 + us * 2 + kb] = (ushort)bfround(vals[j]);
            }
        }
    }

    // ---- fused PairNorm stats finalize: replica partials -> mulds, invlds ----
    if constexpr (PN >= 1) {
        const int set = tid >> 7;  // threads 0-127: set A, 128-255: set B
        const int t = tid & 127;
        if (set == 0 || PN == 2) {
            const float* cp = (set == 0) ? cs_partA : cs_partB;
            float m = 0.f;
            for (int r = 0; r < NREP; ++r) m += cp[r * 128 + t];
            mulds[set][t] = m / (float)N_NODES;
        }
        float ssv = 0.f;
        if (wv == 0) ssv = ss_partA[lane];
        else if (PN == 2 && wv == 1) ssv = ss_partB[lane];
#pragma unroll
        for (int off = 32; off; off >>= 1) ssv += __shfl_down(ssv, off, 64);
        if (lane == 0 && wv < 2) sstotlds[wv] = ssv;
        __syncthreads();
        if (wv < ((PN == 2) ? 2 : 1)) {
            float mq = mulds[wv][lane] * mulds[wv][lane] +
                       mulds[wv][lane + 64] * mulds[wv][lane + 64];
#pragma unroll
            for (int off = 32; off; off >>= 1) mq += __shfl_down(mq, off, 64);
            if (lane == 0) {
                float s = (sstotlds[wv] - (float)N_NODES * mq) / (float)N_NODES;
                invlds[wv] = rsqrtf(EPS + s);
            }
        }
        __syncthreads();
    }
    const float sA = (PN >= 1) ? invlds[0] : 0.f;
    const float sB = (PN == 2) ? invlds[1] : 0.f;

    float bv[CT];
#pragma unroll
    for (int f = 0; f < CT; ++f) bv[f] = bias[f * 16 + (lane & 15)];

    const int row0 = blockIdx.x * 128;
    const int myr = (wv << 4) + (lane & 15);

#pragma unroll
    for (int ms = 0; ms < 2; ++ms) {
        const int rb = row0 + ms * 64;
        __syncthreads();  // xbu safe to overwrite; orders wtu staging before first use
        if constexpr (PN == 0) {
            const float* Xa = (const float*)Xav;
            for (int i = tid; i < 2048; i += 256) {
                int r = i >> 5;
                int c4 = i & 31;
                float4 v = make_float4(0.f, 0.f, 0.f, 0.f);
                if (rb + r < nrows)
                    v = reinterpret_cast<const float4*>(Xa + (size_t)(rb + r) * 128)[c4];
                int sw = (r & 7) << 2;
                xbu[r][(c4 * 2) ^ sw] = pack2(v.x, v.y);
                xbu[r][(c4 * 2 + 1) ^ sw] = pack2(v.z, v.w);
            }
        } else {
            const unsigned* Xa = (const unsigned*)Xav;
#pragma unroll
            for (int pass = 0; pass < 4; ++pass) {
                int s = pass * 2 + (tid >> 7);  // slice 0..7
                int t = tid & 127;
                int r = t >> 1;
                int half = t & 1;
                int c4 = s * 2 + half;  // uint4 index within logical row (0..15)
                float v0 = 0.f, v1 = 0.f, v2 = 0.f, v3 = 0.f, v4 = 0.f, v5 = 0.f, v6 = 0.f,
                      v7 = 0.f;
                if (rb + r < nrows) {
                    uint4 uv = *reinterpret_cast<const uint4*>(
                        Xa + (size_t)s * ((size_t)N_NODES * 8) + (size_t)(rb + r) * 8 + half * 4);
                    float4 ma = *reinterpret_cast<const float4*>(&mulds[0][c4 * 8]);
                    float4 mb = *reinterpret_cast<const float4*>(&mulds[0][c4 * 8 + 4]);
                    v0 = fmaxf((blo(uv.x) - ma.x) * sA, 0.f);
                    v1 = fmaxf((bhi(uv.x) - ma.y) * sA, 0.f);
                    v2 = fmaxf((blo(uv.y) - ma.z) * sA, 0.f);
                    v3 = fmaxf((bhi(uv.y) - ma.w) * sA, 0.f);
                    v4 = fmaxf((blo(uv.z) - mb.x) * sA, 0.f);
                    v5 = fmaxf((bhi(uv.z) - mb.y) * sA, 0.f);
                    v6 = fmaxf((blo(uv.w) - mb.z) * sA, 0.f);
                    v7 = fmaxf((bhi(uv.w) - mb.w) * sA, 0.f);
                    if constexpr (PN == 2) {
                        uint4 u2 = *reinterpret_cast<const uint4*>(
                            Xbu2 + (size_t)s * ((size_t)N_NODES * 8) + (size_t)(rb + r) * 8 +
                            half * 4);
                        float4 na = *reinterpret_cast<const float4*>(&mulds[1][c4 * 8]);
                        float4 nb = *reinterpret_cast<const float4*>(&mulds[1][c4 * 8 + 4]);
                        v0 += fmaxf((blo(u2.x) - na.x) * sB, 0.f);
                        v1 += fmaxf((bhi(u2.x) - na.y) * sB, 0.f);
                        v2 += fmaxf((blo(u2.y) - na.z) * sB, 0.f);
                        v3 += fmaxf((bhi(u2.y) - na.w) * sB, 0.f);
                        v4 += fmaxf((blo(u2.z) - nb.x) * sB, 0.f);
                        v5 += fmaxf((bhi(u2.z) - nb.y) * sB, 0.f);
                        v6 += fmaxf((blo(u2.w) - nb.z) * sB, 0.f);
                        v7 += fmaxf((bhi(u2.w) - nb.w) * sB, 0.f);
                    }
                }
                int sw = (r & 7) << 2;
                xbu[r][(c4 * 4 + 0) ^ sw] = pack2(v0, v1);
                xbu[r][(c4 * 4 + 1) ^ sw] = pack2(v2, v3);
                xbu[r][(c4 * 4 + 2) ^ sw] = pack2(v4, v5);
                xbu[r][(c4 * 4 + 3) ^ sw] = pack2(v6, v7);
            }
        }
        __syncthreads();

        // ---- MFMA: 4 K-chunks of 32 ----
        f32x4 acc[CT];
#pragma unroll
        for (int f = 0; f < CT; ++f) acc[f] = (f32x4){0.f, 0.f, 0.f, 0.f};
        const int xsw = (myr & 7) << 2;
#pragma unroll
        for (int kc = 0; kc < 4; ++kc) {
            const int u0 = kc * 16 + (lane >> 4) * 4;
            s8v a = *reinterpret_cast<const s8v*>(&xbu[myr][u0 ^ xsw]);
#pragma unroll
            for (int f = 0; f < CT; ++f) {
                const int c = f * 16 + (lane & 15);
                s8v b = *reinterpret_cast<const s8v*>(&wtu[c][u0 ^ ((c & 7) << 2)]);
                acc[f] = __builtin_amdgcn_mfma_f32_16x16x32_bf16(a, b, acc[f], 0, 0, 0);
            }
        }

        // ---- epilogue: bias, pack bf16 pairs via shfl_xor(1), store SLICE-MAJOR ----
#pragma unroll
        for (int f = 0; f < CT; ++f) {
#pragma unroll
            for (int r = 0; r < 4; ++r) {
                float v = acc[f][r] + bv[f];
                float p = __shfl_xor(v, 1, 64);
                unsigned pk = (lane & 1) ? pack2(p, v) : pack2(v, p);
                int grow = rb + (wv << 4) + ((lane >> 4) << 2) + r;
                if (grow < nrows && ((lane & 1) == (f & 1))) {
                    Y[(size_t)f * ((size_t)N_NODES * 8) + (size_t)grow * 8 + ((lane & 15) >> 1)] =
                        pk;
                }
            }
        }
    }
}

// ---------------- CSR build ----------------
__global__ __launch_bounds__(256) void hist_kernel(const int* __restrict__ dst,
                                                   int* __restrict__ counts) {
    int i = blockIdx.x * blockDim.x + threadIdx.x;
    const int stride = gridDim.x * blockDim.x;
    for (; i < N_EDGES / 4; i += stride) {
        int4 d = reinterpret_cast<const int4*>(dst)[i];
        atomicAdd(&counts[d.x], 1);
        atomicAdd(&counts[d.y], 1);
        atomicAdd(&counts[d.z], 1);
        atomicAdd(&counts[d.w], 1);
    }
}

// single-block scan, int4-widened
__global__ __launch_bounds__(1024) void scan_kernel(const int* __restrict__ counts,
                                                    int* __restrict__ rowptr) {
    __shared__ int wsum[16];
    const int tid = threadIdx.x;
    const int lane = tid & 63;
    const int w = tid >> 6;
    int offset = 0;
    if (tid == 0) rowptr[0] = 0;
    for (int base = 0; base < N_NODES; base += 4096) {
        int i = base + tid * 4;
        int4 v = make_int4(0, 0, 0, 0);
        if (i < N_NODES) v = *reinterpret_cast<const int4*>(counts + i);
        int p0 = v.x, p1 = p0 + v.y, p2 = p1 + v.z, p3 = p2 + v.w;
        int incl = p3;
#pragma unroll
        for (int d = 1; d < 64; d <<= 1) {
            int t = __shfl_up(incl, d, 64);
            if (lane >= d) incl += t;
        }
        if (lane == 63) wsum[w] = incl;
        __syncthreads();
        if (w == 0 && lane < 16) {
            int t = wsum[lane];
#pragma unroll
            for (int d = 1; d < 16; d <<= 1) {
                int u = __shfl_up(t, d, 64);
                if (lane >= d) t += u;
            }
            wsum[lane] = t;
        }
        __syncthreads();
        int woff = (w == 0) ? 0 : wsum[w - 1];
        int chunk_total = wsum[15];
        int tbase = offset + woff + incl - p3;
        if (i < N_NODES) {
            rowptr[i + 1] = tbase + p0;
            rowptr[i + 2] = tbase + p1;
            rowptr[i + 3] = tbase + p2;
            rowptr[i + 4] = tbase + p3;
        }
        offset += chunk_total;
        __syncthreads();
    }
}

// XCD-binned bucket (scalar dst scan); packs (src, 15-bit weight) into one uint
__global__ __launch_bounds__(256) void bucket_kernel(const int* __restrict__ src,
                                                     const int* __restrict__ dst,
                                                     const float* __restrict__ ew,
                                                     const int* __restrict__ rowptr,
                                                     int* __restrict__ fill,
                                                     unsigned* __restrict__ em) {
    const int myBin = blockIdx.x & (NBINS - 1);
    const int lo = myBin * BINW;
    const int hi = lo + BINW;
    int e = (blockIdx.x >> 3) * 256 + threadIdx.x;
    const int stride = (gridDim.x >> 3) * 256;
    for (; e < N_EDGES; e += stride) {
        int d = dst[e];
        if (d >= lo && d < hi) {
            int pos = atomicAdd(&fill[d], 1);
            unsigned wq = (unsigned)__float2uint_rn(ew[e] * 32767.0f);
            em[rowptr[d] + pos] = (unsigned)src[e] | (wq << 17);
        }
    }
}

// ---- agg SLICED (bf16 H [8][N][8 uints]): slice=blockIdx&7 (XCD-pinned, 3.2MB set),
// 2 lanes per node (uint4 = 16B/lane), 32 nodes/wave, edges unrolled x4, bf16 out ----
__global__ __launch_bounds__(256) void agg128s_kernel(const unsigned* __restrict__ Hs,
                                                      const int* __restrict__ rowptr,
                                                      const unsigned* __restrict__ em,
                                                      unsigned* __restrict__ Bs,
                                                      float* __restrict__ cs_part,
                                                      float* __restrict__ ss_part) {
    __shared__ float csl[4][16];
    __shared__ float ssl4[4];
    const int slice = blockIdx.x & 7;
    const int grp = blockIdx.x >> 3;
    const int wv = threadIdx.x >> 6;
    const int lane = threadIdx.x & 63;
    const int g = lane >> 1;  // node within wave (32 nodes/wave)
    const int f = lane & 1;   // uint4 slot within the 8-uint slice
    const int node = grp * 128 + wv * 32 + g;
    const unsigned* hsl = Hs + (size_t)slice * ((size_t)N_NODES * 8) + f * 4;

    int beg = 0, end = 0;
    if (node < N_NODES) {
        beg = rowptr[node];
        end = rowptr[node + 1];
    }

    float a0 = 0.f, a1 = 0.f, a2 = 0.f, a3 = 0.f, a4 = 0.f, a5 = 0.f, a6 = 0.f, a7 = 0.f;
    int e = beg;
    for (; e + 4 <= end; e += 4) {
        unsigned m0 = em[e];
        unsigned m1 = em[e + 1];
        unsigned m2 = em[e + 2];
        unsigned m3 = em[e + 3];
        uint4 u0 = *reinterpret_cast<const uint4*>(hsl + (size_t)(m0 & SRCMASK) * 8);
        uint4 u1 = *reinterpret_cast<const uint4*>(hsl + (size_t)(m1 & SRCMASK) * 8);
        uint4 u2 = *reinterpret_cast<const uint4*>(hsl + (size_t)(m2 & SRCMASK) * 8);
        uint4 u3 = *reinterpret_cast<const uint4*>(hsl + (size_t)(m3 & SRCMASK) * 8);
        float w0 = (float)(m0 >> 17) * WSCALE;
        float w1 = (float)(m1 >> 17) * WSCALE;
        float w2 = (float)(m2 >> 17) * WSCALE;
        float w3 = (float)(m3 >> 17) * WSCALE;
        a0 += w0 * blo(u0.x); a1 += w0 * bhi(u0.x); a2 += w0 * blo(u0.y); a3 += w0 * bhi(u0.y);
        a4 += w0 * blo(u0.z); a5 += w0 * bhi(u0.z); a6 += w0 * blo(u0.w); a7 += w0 * bhi(u0.w);
        a0 += w1 * blo(u1.x); a1 += w1 * bhi(u1.x); a2 += w1 * blo(u1.y); a3 += w1 * bhi(u1.y);
        a4 += w1 * blo(u1.z); a5 += w1 * bhi(u1.z); a6 += w1 * blo(u1.w); a7 += w1 * bhi(u1.w);
        a0 += w2 * blo(u2.x); a1 += w2 * bhi(u2.x); a2 += w2 * blo(u2.y); a3 += w2 * bhi(u2.y);
        a4 += w2 * blo(u2.z); a5 += w2 * bhi(u2.z); a6 += w2 * blo(u2.w); a7 += w2 * bhi(u2.w);
        a0 += w3 * blo(u3.x); a1 += w3 * bhi(u3.x); a2 += w3 * blo(u3.y); a3 += w3 * bhi(u3.y);
        a4 += w3 * blo(u3.z); a5 += w3 * bhi(u3.z); a6 += w3 * blo(u3.w); a7 += w3 * bhi(u3.w);
    }
    for (; e < end; ++e) {
        unsigned m = em[e];
        uint4 u = *reinterpret_cast<const uint4*>(hsl + (size_t)(m & SRCMASK) * 8);
        float w = (float)(m >> 17) * WSCALE;
        a0 += w * blo(u.x); a1 += w * bhi(u.x); a2 += w * blo(u.y); a3 += w * bhi(u.y);
        a4 += w * blo(u.z); a5 += w * bhi(u.z); a6 += w * blo(u.w); a7 += w * bhi(u.w);
    }

    if (node < N_NODES) {
        uint4 op;
        op.x = pack2(a0, a1);
        op.y = pack2(a2, a3);
        op.z = pack2(a4, a5);
        op.w = pack2(a6, a7);
        *reinterpret_cast<uint4*>(Bs + (size_t)slice * ((size_t)N_NODES * 8) + (size_t)node * 8 +
                                  f * 4) = op;
    }

    // stats: column sums reduce over the 32 node slots (lane bits 1..5), f kept separate
    float c0 = a0, c1 = a1, c2 = a2, c3 = a3, c4 = a4, c5 = a5, c6 = a6, c7 = a7;
    float sq = a0 * a0 + a1 * a1 + a2 * a2 + a3 * a3 + a4 * a4 + a5 * a5 + a6 * a6 + a7 * a7;
#pragma unroll
    for (int off = 2; off <= 32; off <<= 1) {
        c0 += __shfl_xor(c0, off, 64);
        c1 += __shfl_xor(c1, off, 64);
        c2 += __shfl_xor(c2, off, 64);
        c3 += __shfl_xor(c3, off, 64);
        c4 += __shfl_xor(c4, off, 64);
        c5 += __shfl_xor(c5, off, 64);
        c6 += __shfl_xor(c6, off, 64);
        c7 += __shfl_xor(c7, off, 64);
        sq += __shfl_xor(sq, off, 64);
    }
    sq += __shfl_xor(sq, 1, 64);
    if (lane < 2) {
        csl[wv][f * 8 + 0] = c0;
        csl[wv][f * 8 + 1] = c1;
        csl[wv][f * 8 + 2] = c2;
        csl[wv][f * 8 + 3] = c3;
        csl[wv][f * 8 + 4] = c4;
        csl[wv][f * 8 + 5] = c5;
        csl[wv][f * 8 + 6] = c6;
        csl[wv][f * 8 + 7] = c7;
    }
    if (lane == 0) ssl4[wv] = sq;
    __syncthreads();
    const int rep = grp & (NREP - 1);
    if (threadIdx.x < 16) {
        float s = csl[0][threadIdx.x] + csl[1][threadIdx.x] + csl[2][threadIdx.x] +
                  csl[3][threadIdx.x];
        atomicAdd(&cs_part[rep * 128 + slice * 16 + threadIdx.x], s);
    }
    if (threadIdx.x == 0) atomicAdd(&ss_part[rep], ssl4[0] + ssl4[1] + ssl4[2] + ssl4[3]);
}

// ---- agg SLICED (bf16 H [4][N][8 uints]) -> f32 out; 2 lanes/node, uint4 loads ----
__global__ __launch_bounds__(256) void agg64s_kernel(const unsigned* __restrict__ Hs,
                                                     const int* __restrict__ rowptr,
                                                     const unsigned* __restrict__ em,
                                                     float* __restrict__ out) {
    const int slice = blockIdx.x & 3;
    const int grp = blockIdx.x >> 2;
    const int wv = threadIdx.x >> 6;
    const int lane = threadIdx.x & 63;
    const int g = lane >> 1;
    const int f = lane & 1;
    const int node = grp * 128 + wv * 32 + g;
    const unsigned* hsl = Hs + (size_t)slice * ((size_t)N_NODES * 8) + f * 4;

    int beg = 0, end = 0;
    if (node < N_NODES) {
        beg = rowptr[node];
        end = rowptr[node + 1];
    }

    float a0 = 0.f, a1 = 0.f, a2 = 0.f, a3 = 0.f, a4 = 0.f, a5 = 0.f, a6 = 0.f, a7 = 0.f;
    int e = beg;
    for (; e + 4 <= end; e += 4) {
        unsigned m0 = em[e];
        unsigned m1 = em[e + 1];
        unsigned m2 = em[e + 2];
        unsigned m3 = em[e + 3];
        uint4 u0 = *reinterpret_cast<const uint4*>(hsl + (size_t)(m0 & SRCMASK) * 8);
        uint4 u1 = *reinterpret_cast<const uint4*>(hsl + (size_t)(m1 & SRCMASK) * 8);
        uint4 u2 = *reinterpret_cast<const uint4*>(hsl + (size_t)(m2 & SRCMASK) * 8);
        uint4 u3 = *reinterpret_cast<const uint4*>(hsl + (size_t)(m3 & SRCMASK) * 8);
        float w0 = (float)(m0 >> 17) * WSCALE;
        float w1 = (float)(m1 >> 17) * WSCALE;
        float w2 = (float)(m2 >> 17) * WSCALE;
        float w3 = (float)(m3 >> 17) * WSCALE;
        a0 += w0 * blo(u0.x); a1 += w0 * bhi(u0.x); a2 += w0 * blo(u0.y); a3 += w0 * bhi(u0.y);
        a4 += w0 * blo(u0.z); a5 += w0 * bhi(u0.z); a6 += w0 * blo(u0.w); a7 += w0 * bhi(u0.w);
        a0 += w1 * blo(u1.x); a1 += w1 * bhi(u1.x); a2 += w1 * blo(u1.y); a3 += w1 * bhi(u1.y);
        a4 += w1 * blo(u1.z); a5 += w1 * bhi(u1.z); a6 += w1 * blo(u1.w); a7 += w1 * bhi(u1.w);
        a0 += w2 * blo(u2.x); a1 += w2 * bhi(u2.x); a2 += w2 * blo(u2.y); a3 += w2 * bhi(u2.y);
        a4 += w2 * blo(u2.z); a5 += w2 * bhi(u2.z); a6 += w2 * blo(u2.w); a7 += w2 * bhi(u2.w);
        a0 += w3 * blo(u3.x); a1 += w3 * bhi(u3.x); a2 += w3 * blo(u3.y); a3 += w3 * bhi(u3.y);
        a4 += w3 * blo(u3.z); a5 += w3 * bhi(u3.z); a6 += w3 * blo(u3.w); a7 += w3 * bhi(u3.w);
    }
    for (; e < end; ++e) {
        unsigned m = em[e];
        uint4 u = *reinterpret_cast<const uint4*>(hsl + (size_t)(m & SRCMASK) * 8);
        float w = (float)(m >> 17) * WSCALE;
        a0 += w * blo(u.x); a1 += w * bhi(u.x); a2 += w * blo(u.y); a3 += w * bhi(u.y);
        a4 += w * blo(u.z); a5 += w * bhi(u.z); a6 += w * blo(u.w); a7 += w * bhi(u.w);
    }

    if (node < N_NODES) {
        float* op = out + (size_t)node * DOUT + slice * 16 + f * 8;
        *reinterpret_cast<float4*>(op) = make_float4(a0, a1, a2, a3);
        *reinterpret_cast<float4*>(op + 4) = make_float4(a4, a5, a6, a7);
    }
}

extern "C" void kernel_launch(void* const* d_in, const int* in_sizes, int n_in,
                              void* d_out, int out_size, void* d_ws, size_t ws_size,
                              hipStream_t stream) {
    const float* x = (const float*)d_in[0];
    const int* edge_index = (const int*)d_in[1];
    const float* ew = (const float*)d_in[2];
    const float* W0 = (const float*)d_in[3];
    const float* b0 = (const float*)d_in[4];
    const float* W1 = (const float*)d_in[5];
    const float* b1 = (const float*)d_in[6];
    const float* Wout = (const float*)d_in[7];
    const float* bout = (const float*)d_in[8];

    const int* src = edge_index;
    const int* dst = edge_index + N_EDGES;
    float* out = (float*)d_out;

    // workspace layout (bf16 node matrices slice-major; each N*64 uints total)
    unsigned* base = (unsigned*)d_ws;
    unsigned* Hb = base;                          // [8][N][8] (layers 1/2) / [4][N][8] (out)
    unsigned* B1b = base + (size_t)N_NODES * 64;  // [8][N][8] bf16 B1
    unsigned* B2b = B1b + (size_t)N_NODES * 64;   // [8][N][8] bf16 B2
    unsigned* em = B2b + (size_t)N_NODES * 64;    // E packed uint
    int* counts = (int*)(em + N_EDGES);           // N
    int* fill = counts + N_NODES;                 // N
    int* rowptr = fill + N_NODES;                 // N+1
    size_t soff = (size_t)(rowptr + N_NODES + 1 - (int*)base);
    soff = (soff + 3) & ~(size_t)3;
    float* stats = (float*)base + soff;
    float* cs_part1 = stats;                  // NREP*128
    float* ss_part1 = cs_part1 + NREP * 128;  // NREP
    float* cs_part2 = ss_part1 + NREP;        // NREP*128
    float* ss_part2 = cs_part2 + NREP * 128;  // NREP

    const int gemm_grid = (N_NODES + 127) / 128;  // 782
    const int agg128_grid = NGRP128 * 8;          // 6256
    const int agg64_grid = NGRP128 * 4;           // 3128

    // zero init
    hipMemsetAsync(counts, 0, (size_t)2 * N_NODES * sizeof(int), stream);  // counts + fill
    hipMemsetAsync(stats, 0, (size_t)2 * (NREP * 128 + NREP) * sizeof(float), stream);

    // CSR build (dst-ordered)
    hist_kernel<<<1024, 256, 0, stream>>>(dst, counts);
    scan_kernel<<<1, 1024, 0, stream>>>(counts, rowptr);
    bucket_kernel<<<2048, 256, 0, stream>>>(src, dst, ew, rowptr, fill, em);

    // Layer 1
    gemm_mfma<128, 0><<<gemm_grid, 256, 0, stream>>>(
        x, nullptr, nullptr, nullptr, nullptr, nullptr, W0, b0, Hb, N_NODES);
    agg128s_kernel<<<agg128_grid, 256, 0, stream>>>(Hb, rowptr, em, B1b, cs_part1, ss_part1);

    // Layer 2 (stats1 finalized inside gemm)
    gemm_mfma<128, 1><<<gemm_grid, 256, 0, stream>>>(
        B1b, cs_part1, ss_part1, nullptr, nullptr, nullptr, W1, b1, Hb, N_NODES);
    agg128s_kernel<<<agg128_grid, 256, 0, stream>>>(Hb, rowptr, em, B2b, cs_part2, ss_part2);

    // Output layer (stats2 + stats1 finalized inside gemm)
    gemm_mfma<64, 2><<<gemm_grid, 256, 0, stream>>>(
        B2b, cs_part2, ss_part2, B1b, cs_part1, ss_part1, Wout, bout, Hb, N_NODES);
    agg64s_kernel<<<agg64_grid, 256, 0, stream>>>(Hb, rowptr, em, out);
}

// Round 17
// 497.335 us; speedup vs baseline: 1.0207x; 1.0207x over previous
//
#include <hip/hip_runtime.h>

#define N_NODES 100000
#define N_EDGES 1600000
#define DH 128
#define DOUT 64
#define EPS 1e-6f
#define NBINS 8
#define BINW 12500  // ceil(N_NODES / NBINS)
#define NREP 64     // stats replica buffers
#define NGRP ((N_NODES + 63) / 64)  // 64-node groups = 1563
#define SRCMASK 0x1FFFFu            // low 17 bits: src node id
#define WSCALE (1.0f / 32767.0f)    // 15-bit fixed-point weight

typedef __attribute__((ext_vector_type(8))) short s8v;    // 8 bf16 (4 VGPRs)
typedef __attribute__((ext_vector_type(4))) float f32x4;  // MFMA accumulator

__device__ inline unsigned bfround(float f) {  // f32 -> bf16 bits, round-nearest-even
    unsigned u = __float_as_uint(f);
    return (u + 0x7fffu + ((u >> 16) & 1u)) >> 16;
}
__device__ inline unsigned pack2(float a, float b) { return bfround(a) | (bfround(b) << 16); }
__device__ inline float blo(unsigned u) { return __uint_as_float(u << 16); }
__device__ inline float bhi(unsigned u) { return __uint_as_float(u & 0xffff0000u); }

// ------------- MFMA GEMM: Y(bf16, SLICE-MAJOR [CT][N][8 uints]) = f(X)@W + b -------------
// PN=0: X f32 row-major.  PN>=1: X bf16 slice-major [8][N][8 uints], f=relu((X-mu)*inv),
// mu/inv finalized in-block from replica partials.  PN=2: + relu((Xb-muB)*invB) likewise.
template <int COLS, int PN>
__global__ __launch_bounds__(256) void gemm_mfma(const void* __restrict__ Xav,
                                                 const float* __restrict__ cs_partA,
                                                 const float* __restrict__ ss_partA,
                                                 const unsigned* __restrict__ Xbu2,
                                                 const float* __restrict__ cs_partB,
                                                 const float* __restrict__ ss_partB,
                                                 const float* __restrict__ W,
                                                 const float* __restrict__ bias,
                                                 unsigned* __restrict__ Y, int nrows) {
    constexpr int CT = COLS / 16;       // col tiles per wave == slice count of Y
    __shared__ unsigned wtu[COLS][64];  // W^T bf16 pairs: [c][k/2], swizzled
    __shared__ unsigned xbu[64][64];    // X bf16 pairs:   [r][k/2], swizzled
    __shared__ float mulds[2][128];
    __shared__ float invlds[2];
    __shared__ float sstotlds[2];

    const int tid = threadIdx.x;
    const int wv = tid >> 6;
    const int lane = tid & 63;

    // ---- stage W^T as bf16 (once per block) ----
    {
        ushort* wts = (ushort*)wtu;
        constexpr int NV4 = 128 * COLS / 4;
        for (int i = tid; i < NV4; i += 256) {
            int k = i / (COLS / 4);
            int c4 = i % (COLS / 4);
            float4 w4 = reinterpret_cast<const float4*>(W)[i];
            float vals[4] = {w4.x, w4.y, w4.z, w4.w};
            int u = k >> 1, kb = k & 1;
#pragma unroll
            for (int j = 0; j < 4; ++j) {
                int c = c4 * 4 + j;
                int us = u ^ ((c & 7) << 2);
                wts[c * 128 + us * 2 + kb] = (ushort)bfround(vals[j]);
            }
        }
    }

    // ---- fused PairNorm stats finalize: replica partials -> mulds, invlds ----
    if constexpr (PN >= 1) {
        const int set = tid >> 7;  // threads 0-127: set A, 128-255: set B
        const int t = tid & 127;
        if (set == 0 || PN == 2) {
            const float* cp = (set == 0) ? cs_partA : cs_partB;
            float m = 0.f;
            for (int r = 0; r < NREP; ++r) m += cp[r * 128 + t];
            mulds[set][t] = m / (float)N_NODES;
        }
        float ssv = 0.f;
        if (wv == 0) ssv = ss_partA[lane];
        else if (PN == 2 && wv == 1) ssv = ss_partB[lane];
#pragma unroll
        for (int off = 32; off; off >>= 1) ssv += __shfl_down(ssv, off, 64);
        if (lane == 0 && wv < 2) sstotlds[wv] = ssv;
        __syncthreads();
        if (wv < ((PN == 2) ? 2 : 1)) {
            float mq = mulds[wv][lane] * mulds[wv][lane] +
                       mulds[wv][lane + 64] * mulds[wv][lane + 64];
#pragma unroll
            for (int off = 32; off; off >>= 1) mq += __shfl_down(mq, off, 64);
            if (lane == 0) {
                float s = (sstotlds[wv] - (float)N_NODES * mq) / (float)N_NODES;
                invlds[wv] = rsqrtf(EPS + s);
            }
        }
        __syncthreads();
    }
    const float sA = (PN >= 1) ? invlds[0] : 0.f;
    const float sB = (PN == 2) ? invlds[1] : 0.f;

    float bv[CT];
#pragma unroll
    for (int f = 0; f < CT; ++f) bv[f] = bias[f * 16 + (lane & 15)];

    const int row0 = blockIdx.x * 128;
    const int myr = (wv << 4) + (lane & 15);

#pragma unroll
    for (int ms = 0; ms < 2; ++ms) {
        const int rb = row0 + ms * 64;
        __syncthreads();  // xbu safe to overwrite; orders wtu staging before first use
        if constexpr (PN == 0) {
            const float* Xa = (const float*)Xav;
            for (int i = tid; i < 2048; i += 256) {
                int r = i >> 5;
                int c4 = i & 31;
                float4 v = make_float4(0.f, 0.f, 0.f, 0.f);
                if (rb + r < nrows)
                    v = reinterpret_cast<const float4*>(Xa + (size_t)(rb + r) * 128)[c4];
                int sw = (r & 7) << 2;
                xbu[r][(c4 * 2) ^ sw] = pack2(v.x, v.y);
                xbu[r][(c4 * 2 + 1) ^ sw] = pack2(v.z, v.w);
            }
        } else {
            const unsigned* Xa = (const unsigned*)Xav;
#pragma unroll
            for (int pass = 0; pass < 4; ++pass) {
                int s = pass * 2 + (tid >> 7);  // slice 0..7
                int t = tid & 127;
                int r = t >> 1;
                int half = t & 1;
                int c4 = s * 2 + half;  // uint4 index within logical row (0..15)
                float v0 = 0.f, v1 = 0.f, v2 = 0.f, v3 = 0.f, v4 = 0.f, v5 = 0.f, v6 = 0.f,
                      v7 = 0.f;
                if (rb + r < nrows) {
                    uint4 uv = *reinterpret_cast<const uint4*>(
                        Xa + (size_t)s * ((size_t)N_NODES * 8) + (size_t)(rb + r) * 8 + half * 4);
                    float4 ma = *reinterpret_cast<const float4*>(&mulds[0][c4 * 8]);
                    float4 mb = *reinterpret_cast<const float4*>(&mulds[0][c4 * 8 + 4]);
                    v0 = fmaxf((blo(uv.x) - ma.x) * sA, 0.f);
                    v1 = fmaxf((bhi(uv.x) - ma.y) * sA, 0.f);
                    v2 = fmaxf((blo(uv.y) - ma.z) * sA, 0.f);
                    v3 = fmaxf((bhi(uv.y) - ma.w) * sA, 0.f);
                    v4 = fmaxf((blo(uv.z) - mb.x) * sA, 0.f);
                    v5 = fmaxf((bhi(uv.z) - mb.y) * sA, 0.f);
                    v6 = fmaxf((blo(uv.w) - mb.z) * sA, 0.f);
                    v7 = fmaxf((bhi(uv.w) - mb.w) * sA, 0.f);
                    if constexpr (PN == 2) {
                        uint4 u2 = *reinterpret_cast<const uint4*>(
                            Xbu2 + (size_t)s * ((size_t)N_NODES * 8) + (size_t)(rb + r) * 8 +
                            half * 4);
                        float4 na = *reinterpret_cast<const float4*>(&mulds[1][c4 * 8]);
                        float4 nb = *reinterpret_cast<const float4*>(&mulds[1][c4 * 8 + 4]);
                        v0 += fmaxf((blo(u2.x) - na.x) * sB, 0.f);
                        v1 += fmaxf((bhi(u2.x) - na.y) * sB, 0.f);
                        v2 += fmaxf((blo(u2.y) - na.z) * sB, 0.f);
                        v3 += fmaxf((bhi(u2.y) - na.w) * sB, 0.f);
                        v4 += fmaxf((blo(u2.z) - nb.x) * sB, 0.f);
                        v5 += fmaxf((bhi(u2.z) - nb.y) * sB, 0.f);
                        v6 += fmaxf((blo(u2.w) - nb.z) * sB, 0.f);
                        v7 += fmaxf((bhi(u2.w) - nb.w) * sB, 0.f);
                    }
                }
                int sw = (r & 7) << 2;
                xbu[r][(c4 * 4 + 0) ^ sw] = pack2(v0, v1);
                xbu[r][(c4 * 4 + 1) ^ sw] = pack2(v2, v3);
                xbu[r][(c4 * 4 + 2) ^ sw] = pack2(v4, v5);
                xbu[r][(c4 * 4 + 3) ^ sw] = pack2(v6, v7);
            }
        }
        __syncthreads();

        // ---- MFMA: 4 K-chunks of 32 ----
        f32x4 acc[CT];
#pragma unroll
        for (int f = 0; f < CT; ++f) acc[f] = (f32x4){0.f, 0.f, 0.f, 0.f};
        const int xsw = (myr & 7) << 2;
#pragma unroll
        for (int kc = 0; kc < 4; ++kc) {
            const int u0 = kc * 16 + (lane >> 4) * 4;
            s8v a = *reinterpret_cast<const s8v*>(&xbu[myr][u0 ^ xsw]);
#pragma unroll
            for (int f = 0; f < CT; ++f) {
                const int c = f * 16 + (lane & 15);
                s8v b = *reinterpret_cast<const s8v*>(&wtu[c][u0 ^ ((c & 7) << 2)]);
                acc[f] = __builtin_amdgcn_mfma_f32_16x16x32_bf16(a, b, acc[f], 0, 0, 0);
            }
        }

        // ---- epilogue: bias, pack bf16 pairs via shfl_xor(1), store SLICE-MAJOR ----
#pragma unroll
        for (int f = 0; f < CT; ++f) {
#pragma unroll
            for (int r = 0; r < 4; ++r) {
                float v = acc[f][r] + bv[f];
                float p = __shfl_xor(v, 1, 64);
                unsigned pk = (lane & 1) ? pack2(p, v) : pack2(v, p);
                int grow = rb + (wv << 4) + ((lane >> 4) << 2) + r;
                if (grow < nrows && ((lane & 1) == (f & 1))) {
                    Y[(size_t)f * ((size_t)N_NODES * 8) + (size_t)grow * 8 + ((lane & 15) >> 1)] =
                        pk;
                }
            }
        }
    }
}

// ---------------- CSR build ----------------
__global__ __launch_bounds__(256) void hist_kernel(const int* __restrict__ dst,
                                                   int* __restrict__ counts) {
    int i = blockIdx.x * blockDim.x + threadIdx.x;
    const int stride = gridDim.x * blockDim.x;
    for (; i < N_EDGES / 4; i += stride) {
        int4 d = reinterpret_cast<const int4*>(dst)[i];
        atomicAdd(&counts[d.x], 1);
        atomicAdd(&counts[d.y], 1);
        atomicAdd(&counts[d.z], 1);
        atomicAdd(&counts[d.w], 1);
    }
}

// single-block scan, int4-widened
__global__ __launch_bounds__(1024) void scan_kernel(const int* __restrict__ counts,
                                                    int* __restrict__ rowptr) {
    __shared__ int wsum[16];
    const int tid = threadIdx.x;
    const int lane = tid & 63;
    const int w = tid >> 6;
    int offset = 0;
    if (tid == 0) rowptr[0] = 0;
    for (int base = 0; base < N_NODES; base += 4096) {
        int i = base + tid * 4;
        int4 v = make_int4(0, 0, 0, 0);
        if (i < N_NODES) v = *reinterpret_cast<const int4*>(counts + i);
        int p0 = v.x, p1 = p0 + v.y, p2 = p1 + v.z, p3 = p2 + v.w;
        int incl = p3;
#pragma unroll
        for (int d = 1; d < 64; d <<= 1) {
            int t = __shfl_up(incl, d, 64);
            if (lane >= d) incl += t;
        }
        if (lane == 63) wsum[w] = incl;
        __syncthreads();
        if (w == 0 && lane < 16) {
            int t = wsum[lane];
#pragma unroll
            for (int d = 1; d < 16; d <<= 1) {
                int u = __shfl_up(t, d, 64);
                if (lane >= d) t += u;
            }
            wsum[lane] = t;
        }
        __syncthreads();
        int woff = (w == 0) ? 0 : wsum[w - 1];
        int chunk_total = wsum[15];
        int tbase = offset + woff + incl - p3;
        if (i < N_NODES) {
            rowptr[i + 1] = tbase + p0;
            rowptr[i + 2] = tbase + p1;
            rowptr[i + 3] = tbase + p2;
            rowptr[i + 4] = tbase + p3;
        }
        offset += chunk_total;
        __syncthreads();
    }
}

// XCD-binned bucket (scalar dst scan); packs (src, 15-bit weight) into one uint
__global__ __launch_bounds__(256) void bucket_kernel(const int* __restrict__ src,
                                                     const int* __restrict__ dst,
                                                     const float* __restrict__ ew,
                                                     const int* __restrict__ rowptr,
                                                     int* __restrict__ fill,
                                                     unsigned* __restrict__ em) {
    const int myBin = blockIdx.x & (NBINS - 1);
    const int lo = myBin * BINW;
    const int hi = lo + BINW;
    int e = (blockIdx.x >> 3) * 256 + threadIdx.x;
    const int stride = (gridDim.x >> 3) * 256;
    for (; e < N_EDGES; e += stride) {
        int d = dst[e];
        if (d >= lo && d < hi) {
            int pos = atomicAdd(&fill[d], 1);
            unsigned wq = (unsigned)__float2uint_rn(ew[e] * 32767.0f);
            em[rowptr[d] + pos] = (unsigned)src[e] | (wq << 17);
        }
    }
}

// ---- agg SLICED (bf16 H [8][N][8 uints]): slice=blockIdx&7 (XCD-pinned, 3.2MB set),
// one 4-lane group per node, sequential edges unrolled x4, bf16 B out slice-major ----
__global__ __launch_bounds__(256) void agg128s_kernel(const unsigned* __restrict__ Hs,
                                                      const int* __restrict__ rowptr,
                                                      const unsigned* __restrict__ em,
                                                      unsigned* __restrict__ Bs,
                                                      float* __restrict__ cs_part,
                                                      float* __restrict__ ss_part) {
    __shared__ float csl[4][16];
    __shared__ float ssl4[4];
    const int slice = blockIdx.x & 7;
    const int grp = blockIdx.x >> 3;
    const int wv = threadIdx.x >> 6;
    const int lane = threadIdx.x & 63;
    const int g = lane >> 2;  // node group within wave (16 nodes/wave)
    const int f = lane & 3;   // uint2 slot within the 8-uint slice
    const int node = grp * 64 + wv * 16 + g;
    const unsigned* hsl = Hs + (size_t)slice * ((size_t)N_NODES * 8) + f * 2;

    int beg = 0, end = 0;
    if (node < N_NODES) {
        beg = rowptr[node];
        end = rowptr[node + 1];
    }

    float a0 = 0.f, a1 = 0.f, a2 = 0.f, a3 = 0.f;
    int e = beg;
    for (; e + 4 <= end; e += 4) {
        unsigned m0 = em[e];
        unsigned m1 = em[e + 1];
        unsigned m2 = em[e + 2];
        unsigned m3 = em[e + 3];
        uint2 u0 = *reinterpret_cast<const uint2*>(hsl + (size_t)(m0 & SRCMASK) * 8);
        uint2 u1 = *reinterpret_cast<const uint2*>(hsl + (size_t)(m1 & SRCMASK) * 8);
        uint2 u2 = *reinterpret_cast<const uint2*>(hsl + (size_t)(m2 & SRCMASK) * 8);
        uint2 u3 = *reinterpret_cast<const uint2*>(hsl + (size_t)(m3 & SRCMASK) * 8);
        float w0 = (float)(m0 >> 17) * WSCALE;
        float w1 = (float)(m1 >> 17) * WSCALE;
        float w2 = (float)(m2 >> 17) * WSCALE;
        float w3 = (float)(m3 >> 17) * WSCALE;
        a0 += w0 * blo(u0.x); a1 += w0 * bhi(u0.x); a2 += w0 * blo(u0.y); a3 += w0 * bhi(u0.y);
        a0 += w1 * blo(u1.x); a1 += w1 * bhi(u1.x); a2 += w1 * blo(u1.y); a3 += w1 * bhi(u1.y);
        a0 += w2 * blo(u2.x); a1 += w2 * bhi(u2.x); a2 += w2 * blo(u2.y); a3 += w2 * bhi(u2.y);
        a0 += w3 * blo(u3.x); a1 += w3 * bhi(u3.x); a2 += w3 * blo(u3.y); a3 += w3 * bhi(u3.y);
    }
    for (; e < end; ++e) {
        unsigned m = em[e];
        uint2 u = *reinterpret_cast<const uint2*>(hsl + (size_t)(m & SRCMASK) * 8);
        float w = (float)(m >> 17) * WSCALE;
        a0 += w * blo(u.x); a1 += w * bhi(u.x); a2 += w * blo(u.y); a3 += w * bhi(u.y);
    }

    if (node < N_NODES) {
        uint2 op;
        op.x = pack2(a0, a1);
        op.y = pack2(a2, a3);
        *reinterpret_cast<uint2*>(Bs + (size_t)slice * ((size_t)N_NODES * 8) + (size_t)node * 8 +
                                  f * 2) = op;
    }

    // stats: reduce over the 16 node-groups (lane bits 2..5), per-wave only
    float c0 = a0, c1 = a1, c2 = a2, c3 = a3;
    float sq = a0 * a0 + a1 * a1 + a2 * a2 + a3 * a3;
#pragma unroll
    for (int off = 4; off <= 32; off <<= 1) {
        c0 += __shfl_xor(c0, off, 64);
        c1 += __shfl_xor(c1, off, 64);
        c2 += __shfl_xor(c2, off, 64);
        c3 += __shfl_xor(c3, off, 64);
        sq += __shfl_xor(sq, off, 64);
    }
    sq += __shfl_xor(sq, 1, 64);
    sq += __shfl_xor(sq, 2, 64);
    if (lane < 4) {
        csl[wv][f * 4 + 0] = c0;
        csl[wv][f * 4 + 1] = c1;
        csl[wv][f * 4 + 2] = c2;
        csl[wv][f * 4 + 3] = c3;
    }
    if (lane == 0) ssl4[wv] = sq;
    __syncthreads();
    const int rep = grp & (NREP - 1);
    if (threadIdx.x < 16) {
        float s = csl[0][threadIdx.x] + csl[1][threadIdx.x] + csl[2][threadIdx.x] +
                  csl[3][threadIdx.x];
        atomicAdd(&cs_part[rep * 128 + slice * 16 + threadIdx.x], s);
    }
    if (threadIdx.x == 0) atomicAdd(&ss_part[rep], ssl4[0] + ssl4[1] + ssl4[2] + ssl4[3]);
}

// ---- agg SLICED (bf16 H [4][N][8 uints]) -> f32 out, slice=blockIdx&3 (XCDs s and s+4) ----
__global__ __launch_bounds__(256) void agg64s_kernel(const unsigned* __restrict__ Hs,
                                                     const int* __restrict__ rowptr,
                                                     const unsigned* __restrict__ em,
                                                     float* __restrict__ out) {
    const int slice = blockIdx.x & 3;
    const int grp = blockIdx.x >> 2;
    const int wv = threadIdx.x >> 6;
    const int lane = threadIdx.x & 63;
    const int g = lane >> 2;
    const int f = lane & 3;
    const int node = grp * 64 + wv * 16 + g;
    const unsigned* hsl = Hs + (size_t)slice * ((size_t)N_NODES * 8) + f * 2;

    int beg = 0, end = 0;
    if (node < N_NODES) {
        beg = rowptr[node];
        end = rowptr[node + 1];
    }

    float a0 = 0.f, a1 = 0.f, a2 = 0.f, a3 = 0.f;
    int e = beg;
    for (; e + 4 <= end; e += 4) {
        unsigned m0 = em[e];
        unsigned m1 = em[e + 1];
        unsigned m2 = em[e + 2];
        unsigned m3 = em[e + 3];
        uint2 u0 = *reinterpret_cast<const uint2*>(hsl + (size_t)(m0 & SRCMASK) * 8);
        uint2 u1 = *reinterpret_cast<const uint2*>(hsl + (size_t)(m1 & SRCMASK) * 8);
        uint2 u2 = *reinterpret_cast<const uint2*>(hsl + (size_t)(m2 & SRCMASK) * 8);
        uint2 u3 = *reinterpret_cast<const uint2*>(hsl + (size_t)(m3 & SRCMASK) * 8);
        float w0 = (float)(m0 >> 17) * WSCALE;
        float w1 = (float)(m1 >> 17) * WSCALE;
        float w2 = (float)(m2 >> 17) * WSCALE;
        float w3 = (float)(m3 >> 17) * WSCALE;
        a0 += w0 * blo(u0.x); a1 += w0 * bhi(u0.x); a2 += w0 * blo(u0.y); a3 += w0 * bhi(u0.y);
        a0 += w1 * blo(u1.x); a1 += w1 * bhi(u1.x); a2 += w1 * blo(u1.y); a3 += w1 * bhi(u1.y);
        a0 += w2 * blo(u2.x); a1 += w2 * bhi(u2.x); a2 += w2 * blo(u2.y); a3 += w2 * bhi(u2.y);
        a0 += w3 * blo(u3.x); a1 += w3 * bhi(u3.x); a2 += w3 * blo(u3.y); a3 += w3 * bhi(u3.y);
    }
    for (; e < end; ++e) {
        unsigned m = em[e];
        uint2 u = *reinterpret_cast<const uint2*>(hsl + (size_t)(m & SRCMASK) * 8);
        float w = (float)(m >> 17) * WSCALE;
        a0 += w * blo(u.x); a1 += w * bhi(u.x); a2 += w * blo(u.y); a3 += w * bhi(u.y);
    }

    if (node < N_NODES) {
        *reinterpret_cast<float4*>(out + (size_t)node * DOUT + slice * 16 + f * 4) =
            make_float4(a0, a1, a2, a3);
    }
}

extern "C" void kernel_launch(void* const* d_in, const int* in_sizes, int n_in,
                              void* d_out, int out_size, void* d_ws, size_t ws_size,
                              hipStream_t stream) {
    const float* x = (const float*)d_in[0];
    const int* edge_index = (const int*)d_in[1];
    const float* ew = (const float*)d_in[2];
    const float* W0 = (const float*)d_in[3];
    const float* b0 = (const float*)d_in[4];
    const float* W1 = (const float*)d_in[5];
    const float* b1 = (const float*)d_in[6];
    const float* Wout = (const float*)d_in[7];
    const float* bout = (const float*)d_in[8];

    const int* src = edge_index;
    const int* dst = edge_index + N_EDGES;
    float* out = (float*)d_out;

    // workspace layout (bf16 node matrices slice-major; each N*64 uints total)
    unsigned* base = (unsigned*)d_ws;
    unsigned* Hb = base;                          // [8][N][8] (layers 1/2) / [4][N][8] (out)
    unsigned* B1b = base + (size_t)N_NODES * 64;  // [8][N][8] bf16 B1
    unsigned* B2b = B1b + (size_t)N_NODES * 64;   // [8][N][8] bf16 B2
    unsigned* em = B2b + (size_t)N_NODES * 64;    // E packed uint
    int* counts = (int*)(em + N_EDGES);           // N
    int* fill = counts + N_NODES;                 // N
    int* rowptr = fill + N_NODES;                 // N+1
    size_t soff = (size_t)(rowptr + N_NODES + 1 - (int*)base);
    soff = (soff + 3) & ~(size_t)3;
    float* stats = (float*)base + soff;
    float* cs_part1 = stats;                  // NREP*128
    float* ss_part1 = cs_part1 + NREP * 128;  // NREP
    float* cs_part2 = ss_part1 + NREP;        // NREP*128
    float* ss_part2 = cs_part2 + NREP * 128;  // NREP

    const int gemm_grid = (N_NODES + 127) / 128;  // 782
    const int agg128_grid = NGRP * 8;             // 12504
    const int agg64_grid = NGRP * 4;              // 6252

    // zero init
    hipMemsetAsync(counts, 0, (size_t)2 * N_NODES * sizeof(int), stream);  // counts + fill
    hipMemsetAsync(stats, 0, (size_t)2 * (NREP * 128 + NREP) * sizeof(float), stream);

    // CSR build (dst-ordered)
    hist_kernel<<<1024, 256, 0, stream>>>(dst, counts);
    scan_kernel<<<1, 1024, 0, stream>>>(counts, rowptr);
    bucket_kernel<<<2048, 256, 0, stream>>>(src, dst, ew, rowptr, fill, em);

    // Layer 1
    gemm_mfma<128, 0><<<gemm_grid, 256, 0, stream>>>(
        x, nullptr, nullptr, nullptr, nullptr, nullptr, W0, b0, Hb, N_NODES);
    agg128s_kernel<<<agg128_grid, 256, 0, stream>>>(Hb, rowptr, em, B1b, cs_part1, ss_part1);

    // Layer 2 (stats1 finalized inside gemm)
    gemm_mfma<128, 1><<<gemm_grid, 256, 0, stream>>>(
        B1b, cs_part1, ss_part1, nullptr, nullptr, nullptr, W1, b1, Hb, N_NODES);
    agg128s_kernel<<<agg128_grid, 256, 0, stream>>>(Hb, rowptr, em, B2b, cs_part2, ss_part2);

    // Output layer (stats2 + stats1 finalized inside gemm)
    gemm_mfma<64, 2><<<gemm_grid, 256, 0, stream>>>(
        B2b, cs_part2, ss_part2, B1b, cs_part1, ss_part1, Wout, bout, Hb, N_NODES);
    agg64s_kernel<<<agg64_grid, 256, 0, stream>>>(Hb, rowptr, em, out);
}